// Round 1
// baseline (175.647 us; speedup 1.0000x reference)
//
#include <hip/hip_runtime.h>

#define BATCH 16
#define NPTS  4096
#define TOT   (BATCH * NPTS)   // 65536 points per tensor

__global__ void zero_kernel(float* out) { out[0] = 0.0f; }

// Pack {x, y, z, |q|^2} into float4 per point for both tensors.
// pk layout: [2][BATCH][NPTS] float4 ; slot 0 = x-points, slot 1 = y-points
__global__ __launch_bounds__(256) void pack_kernel(const float* __restrict__ x,
                                                   const float* __restrict__ y,
                                                   float4* __restrict__ pk) {
    int idx = blockIdx.x * 256 + threadIdx.x;       // 0 .. 2*TOT-1
    const float* src = (idx < TOT) ? x : y;
    int r = (idx < TOT) ? idx : (idx - TOT);
    float a = src[r * 3 + 0];
    float b = src[r * 3 + 1];
    float c = src[r * 3 + 2];
    pk[idx] = make_float4(a, b, c, fmaf(a, a, fmaf(b, b, c * c)));
}

// One block = (direction, batch, 256-row chunk). Each thread owns one P point,
// scans all NPTS Q points (wave-uniform address -> scalar loads), keeps 4
// independent running mins, then block-reduces the sum of mins and atomically
// accumulates into the scalar loss.
__global__ __launch_bounds__(256) void chamfer_packed(const float4* __restrict__ pk,
                                                      float* __restrict__ out) {
    int blk   = blockIdx.x;        // 0..511
    int dir   = blk >> 8;          // 0: P=x,Q=y ; 1: P=y,Q=x
    int t     = blk & 255;
    int b     = t >> 4;            // batch
    int chunk = t & 15;            // 16 chunks of 256 rows

    const float4* __restrict__ P = pk + dir * TOT + b * NPTS + chunk * 256;
    const float4* __restrict__ Q = pk + (1 - dir) * TOT + b * NPTS;

    float4 p  = P[threadIdx.x];
    float  p2 = p.w;
    float  px = -2.0f * p.x, py = -2.0f * p.y, pz = -2.0f * p.z;

    float b0 = 3.4e38f, b1 = 3.4e38f, b2 = 3.4e38f, b3 = 3.4e38f;
    for (int j = 0; j < NPTS; j += 4) {
        float4 q0 = Q[j + 0];
        float4 q1 = Q[j + 1];
        float4 q2 = Q[j + 2];
        float4 q3 = Q[j + 3];
        float d0 = fmaf(px, q0.x, fmaf(py, q0.y, fmaf(pz, q0.z, p2 + q0.w)));
        float d1 = fmaf(px, q1.x, fmaf(py, q1.y, fmaf(pz, q1.z, p2 + q1.w)));
        float d2 = fmaf(px, q2.x, fmaf(py, q2.y, fmaf(pz, q2.z, p2 + q2.w)));
        float d3 = fmaf(px, q3.x, fmaf(py, q3.y, fmaf(pz, q3.z, p2 + q3.w)));
        b0 = fminf(b0, d0);
        b1 = fminf(b1, d1);
        b2 = fminf(b2, d2);
        b3 = fminf(b3, d3);
    }
    float best = fminf(fminf(b0, b1), fminf(b2, b3));

    // block-wide sum of per-thread mins
    float v = best;
    #pragma unroll
    for (int off = 32; off; off >>= 1) v += __shfl_down(v, off);
    __shared__ float red[4];
    int lane = threadIdx.x & 63, wid = threadIdx.x >> 6;
    if (lane == 0) red[wid] = v;
    __syncthreads();
    if (threadIdx.x == 0) {
        float s = (red[0] + red[1]) + (red[2] + red[3]);
        atomicAdd(out, s * (1.0f / (float)TOT));
    }
}

// Fallback if workspace is too small: direct difference form, loads raw points.
__global__ __launch_bounds__(256) void chamfer_direct(const float* __restrict__ x,
                                                      const float* __restrict__ y,
                                                      float* __restrict__ out) {
    int blk   = blockIdx.x;
    int dir   = blk >> 8;
    int t     = blk & 255;
    int b     = t >> 4;
    int chunk = t & 15;

    const float* __restrict__ P = (dir ? y : x) + (b * NPTS + chunk * 256) * 3;
    const float* __restrict__ Q = (dir ? x : y) + b * NPTS * 3;

    float px = P[threadIdx.x * 3 + 0];
    float py = P[threadIdx.x * 3 + 1];
    float pz = P[threadIdx.x * 3 + 2];

    float b0 = 3.4e38f, b1 = 3.4e38f, b2 = 3.4e38f, b3 = 3.4e38f;
    for (int j = 0; j < NPTS; j += 4) {
        #pragma unroll
        for (int u = 0; u < 4; ++u) {
            float dx = px - Q[(j + u) * 3 + 0];
            float dy = py - Q[(j + u) * 3 + 1];
            float dz = pz - Q[(j + u) * 3 + 2];
            float d  = fmaf(dx, dx, fmaf(dy, dy, dz * dz));
            if (u == 0) b0 = fminf(b0, d);
            if (u == 1) b1 = fminf(b1, d);
            if (u == 2) b2 = fminf(b2, d);
            if (u == 3) b3 = fminf(b3, d);
        }
    }
    float best = fminf(fminf(b0, b1), fminf(b2, b3));

    float v = best;
    #pragma unroll
    for (int off = 32; off; off >>= 1) v += __shfl_down(v, off);
    __shared__ float red[4];
    int lane = threadIdx.x & 63, wid = threadIdx.x >> 6;
    if (lane == 0) red[wid] = v;
    __syncthreads();
    if (threadIdx.x == 0) {
        float s = (red[0] + red[1]) + (red[2] + red[3]);
        atomicAdd(out, s * (1.0f / (float)TOT));
    }
}

extern "C" void kernel_launch(void* const* d_in, const int* in_sizes, int n_in,
                              void* d_out, int out_size, void* d_ws, size_t ws_size,
                              hipStream_t stream) {
    const float* x = (const float*)d_in[0];
    const float* y = (const float*)d_in[1];
    float* out = (float*)d_out;

    hipLaunchKernelGGL(zero_kernel, dim3(1), dim3(1), 0, stream, out);

    size_t need = (size_t)2 * TOT * sizeof(float4);   // 2 MiB
    if (ws_size >= need) {
        float4* pk = (float4*)d_ws;
        hipLaunchKernelGGL(pack_kernel, dim3(2 * TOT / 256), dim3(256), 0, stream, x, y, pk);
        hipLaunchKernelGGL(chamfer_packed, dim3(512), dim3(256), 0, stream, pk, out);
    } else {
        hipLaunchKernelGGL(chamfer_direct, dim3(512), dim3(256), 0, stream, x, y, out);
    }
}

// Round 2
// 90.478 us; speedup vs baseline: 1.9413x; 1.9413x over previous
//
#include <hip/hip_runtime.h>

#define BATCH 16
#define NPTS  4096
#define TOT   (BATCH * NPTS)   // 65536 points per tensor
#define QSEG  4                // Q split into 4 segments of 1024
#define QLEN  (NPTS / QSEG)

__global__ void zero_kernel(float* out) { out[0] = 0.0f; }

// Pack {x, y, z, |q|^2} into float4 per point for both tensors.
// pk layout: [2][BATCH][NPTS] float4 ; slot 0 = x-points, slot 1 = y-points
__global__ __launch_bounds__(256) void pack_kernel(const float* __restrict__ x,
                                                   const float* __restrict__ y,
                                                   float4* __restrict__ pk) {
    int idx = blockIdx.x * 256 + threadIdx.x;       // 0 .. 2*TOT-1
    const float* src = (idx < TOT) ? x : y;
    int r = (idx < TOT) ? idx : (idx - TOT);
    float a = src[r * 3 + 0];
    float b = src[r * 3 + 1];
    float c = src[r * 3 + 2];
    pk[idx] = make_float4(a, b, c, fmaf(a, a, fmaf(b, b, c * c)));
}

// Pass 1: one block = (dir, batch, 256-row chunk, q-segment). Each thread owns
// one P row, scans 1024 Q points of its segment (wave-uniform -> scalar loads),
// 4 independent min chains, 4 ops/pair (p^2 hoisted out of the loop entirely).
// Writes the partial min to part[grow*4 + qseg].
__global__ __launch_bounds__(256) void chamfer_pass1(const float4* __restrict__ pk,
                                                     float* __restrict__ part) {
    int blk   = blockIdx.x;        // 0..2047
    int qseg  = blk & 3;
    int t     = blk >> 2;          // 0..511
    int dir   = t >> 8;            // 0: P=x,Q=y ; 1: P=y,Q=x
    int bb    = (t >> 4) & 15;     // batch
    int chunk = t & 15;            // 16 chunks of 256 rows

    int row = chunk * 256 + threadIdx.x;
    const float4* __restrict__ P = pk + dir * TOT + bb * NPTS;
    const float4* __restrict__ Q = pk + (1 - dir) * TOT + bb * NPTS + qseg * QLEN;

    float4 p  = P[row];
    float  px = -2.0f * p.x, py = -2.0f * p.y, pz = -2.0f * p.z;

    float b0 = 3.4e38f, b1 = 3.4e38f, b2 = 3.4e38f, b3 = 3.4e38f;
    #pragma unroll 4
    for (int j = 0; j < QLEN; j += 4) {
        float4 q0 = Q[j + 0];
        float4 q1 = Q[j + 1];
        float4 q2 = Q[j + 2];
        float4 q3 = Q[j + 3];
        b0 = fminf(b0, fmaf(px, q0.x, fmaf(py, q0.y, fmaf(pz, q0.z, q0.w))));
        b1 = fminf(b1, fmaf(px, q1.x, fmaf(py, q1.y, fmaf(pz, q1.z, q1.w))));
        b2 = fminf(b2, fmaf(px, q2.x, fmaf(py, q2.y, fmaf(pz, q2.z, q2.w))));
        b3 = fminf(b3, fmaf(px, q3.x, fmaf(py, q3.y, fmaf(pz, q3.z, q3.w))));
    }
    float best = fminf(fminf(b0, b1), fminf(b2, b3));

    int grow = dir * TOT + bb * NPTS + row;     // global row id, same layout as pk
    part[grow * QSEG + qseg] = best;
}

// Pass 2: combine the 4 segment partials per row, add p^2, block-reduce sum,
// atomic accumulate the mean.
__global__ __launch_bounds__(256) void chamfer_pass2(const float4* __restrict__ part4,
                                                     const float4* __restrict__ pk,
                                                     float* __restrict__ out) {
    int gid = blockIdx.x * 256 + threadIdx.x;   // 0..131071 == (dir,b,row)
    float4 v = part4[gid];
    float  m = fminf(fminf(v.x, v.y), fminf(v.z, v.w)) + pk[gid].w;

    float s = m;
    #pragma unroll
    for (int off = 32; off; off >>= 1) s += __shfl_down(s, off);
    __shared__ float red[4];
    int lane = threadIdx.x & 63, wid = threadIdx.x >> 6;
    if (lane == 0) red[wid] = s;
    __syncthreads();
    if (threadIdx.x == 0) {
        float tot = (red[0] + red[1]) + (red[2] + red[3]);
        atomicAdd(out, tot * (1.0f / (float)TOT));
    }
}

// ---------------- fallback (round-1 passing path) ----------------
__global__ __launch_bounds__(256) void chamfer_packed(const float4* __restrict__ pk,
                                                      float* __restrict__ out) {
    int blk   = blockIdx.x;
    int dir   = blk >> 8;
    int t     = blk & 255;
    int b     = t >> 4;
    int chunk = t & 15;

    const float4* __restrict__ P = pk + dir * TOT + b * NPTS + chunk * 256;
    const float4* __restrict__ Q = pk + (1 - dir) * TOT + b * NPTS;

    float4 p  = P[threadIdx.x];
    float  p2 = p.w;
    float  px = -2.0f * p.x, py = -2.0f * p.y, pz = -2.0f * p.z;

    float b0 = 3.4e38f, b1 = 3.4e38f, b2 = 3.4e38f, b3 = 3.4e38f;
    for (int j = 0; j < NPTS; j += 4) {
        float4 q0 = Q[j + 0];
        float4 q1 = Q[j + 1];
        float4 q2 = Q[j + 2];
        float4 q3 = Q[j + 3];
        b0 = fminf(b0, fmaf(px, q0.x, fmaf(py, q0.y, fmaf(pz, q0.z, p2 + q0.w))));
        b1 = fminf(b1, fmaf(px, q1.x, fmaf(py, q1.y, fmaf(pz, q1.z, p2 + q1.w))));
        b2 = fminf(b2, fmaf(px, q2.x, fmaf(py, q2.y, fmaf(pz, q2.z, p2 + q2.w))));
        b3 = fminf(b3, fmaf(px, q3.x, fmaf(py, q3.y, fmaf(pz, q3.z, p2 + q3.w))));
    }
    float best = fminf(fminf(b0, b1), fminf(b2, b3));

    float v = best;
    #pragma unroll
    for (int off = 32; off; off >>= 1) v += __shfl_down(v, off);
    __shared__ float red[4];
    int lane = threadIdx.x & 63, wid = threadIdx.x >> 6;
    if (lane == 0) red[wid] = v;
    __syncthreads();
    if (threadIdx.x == 0) {
        float s = (red[0] + red[1]) + (red[2] + red[3]);
        atomicAdd(out, s * (1.0f / (float)TOT));
    }
}

extern "C" void kernel_launch(void* const* d_in, const int* in_sizes, int n_in,
                              void* d_out, int out_size, void* d_ws, size_t ws_size,
                              hipStream_t stream) {
    const float* x = (const float*)d_in[0];
    const float* y = (const float*)d_in[1];
    float* out = (float*)d_out;

    hipLaunchKernelGGL(zero_kernel, dim3(1), dim3(1), 0, stream, out);

    size_t pk_bytes   = (size_t)2 * TOT * sizeof(float4);   // 2 MiB
    size_t part_bytes = (size_t)2 * TOT * QSEG * sizeof(float); // 2 MiB

    if (ws_size >= pk_bytes + part_bytes) {
        float4* pk   = (float4*)d_ws;
        float*  part = (float*)((char*)d_ws + pk_bytes);
        hipLaunchKernelGGL(pack_kernel, dim3(2 * TOT / 256), dim3(256), 0, stream, x, y, pk);
        hipLaunchKernelGGL(chamfer_pass1, dim3(512 * QSEG), dim3(256), 0, stream, pk, part);
        hipLaunchKernelGGL(chamfer_pass2, dim3(2 * TOT / 256), dim3(256), 0, stream,
                           (const float4*)part, pk, out);
    } else if (ws_size >= pk_bytes) {
        float4* pk = (float4*)d_ws;
        hipLaunchKernelGGL(pack_kernel, dim3(2 * TOT / 256), dim3(256), 0, stream, x, y, pk);
        hipLaunchKernelGGL(chamfer_packed, dim3(512), dim3(256), 0, stream, pk, out);
    }
}